// Round 4
// baseline (157.469 us; speedup 1.0000x reference)
//
#include <hip/hip_runtime.h>

typedef __attribute__((ext_vector_type(8))) short short8;
typedef __attribute__((ext_vector_type(4))) float f32x4;

#define C_DIM 128
#define K_CODES 1024
#define TOT 8388608   // 16*128*64*64
#define NBLK 2048     // 32 pixels per block

__device__ __forceinline__ unsigned int f2bf1(float f) {
  unsigned int u = __float_as_uint(f);
  return (u + 0x7FFFu + ((u >> 16) & 1u)) >> 16;   // RNE fp32->bf16
}
__device__ __forceinline__ unsigned int f2bf2(float lo, float hi) {
  return f2bf1(lo) | (f2bf1(hi) << 16);
}

union U16x8 { uint4 u; short8 s; };

// ---- P: bf16 codebook + (1 + ||e||^2) + zero used ----
__global__ void prep_kernel(const float* __restrict__ cb,
                            unsigned short* __restrict__ ebf,
                            float* __restrict__ nsq1,
                            int* __restrict__ used) {
  int gid = blockIdx.x * 256 + threadIdx.x;     // 512*256 == K*C exactly
  ebf[gid] = (unsigned short)f2bf1(cb[gid]);
  if (gid < K_CODES) {
    float s = 0.f;
    #pragma unroll 8
    for (int c = 0; c < C_DIM; ++c) { float v = cb[gid * C_DIM + c]; s += v * v; }
    nsq1[gid] = 1.0f + s;      // +1 keeps d positive -> u32-monotone float bits
    used[gid] = 0;
  }
}

// ---- M: per block: 32 pixels x 1024 codes argmin + gather + loss ----
// A = bf16(-2z) so MFMA with C init = 1+||e||^2 yields d = 1+||e||^2-2<z,e> directly.
// key = (bits(d) & ~1023) | code  -> argmin via v_min_u32 everywhere.
// Barrier-free K phase: A frags loaded per-lane from global; B double-buffered
// register prefetch from the L2-hot 256KB bf16 codebook.
// launch_bounds(256,4): live set ~105 regs, MUST stay under 128 (no spill).
__global__ __launch_bounds__(256, 4)
void vq_main(const float* __restrict__ zin, const float* __restrict__ cb,
             const unsigned short* __restrict__ ebf,
             const float* __restrict__ nsq1,
             int* __restrict__ used, float* __restrict__ lossp,
             float* __restrict__ out) {
  __shared__ unsigned int mergeK[32][4];
  __shared__ int   widx[32];
  __shared__ float wsum[4];

  const int t  = threadIdx.x;
  const int L  = t & 63;
  const int wv = t >> 6;        // wave 0..3: codes [wv*256, wv*256+256)
  const int q  = L >> 4;        // lane quad
  const int nL = L & 15;

  const int bb = blockIdx.x >> 7;          // batch 0..15
  const int rem = blockIdx.x & 127;
  const int h  = rem >> 1;                 // 0..63
  const int wh = rem & 1;                  // pixel-col half
  const int zbase = bb * (C_DIM * 4096) + h * 64 + wh * 32;  // + c*4096 + p

  // ---- A fragments straight from global, packed bf16(-2z) in-register
  // lane L, m-tile mt: pixel = mt*16+nL, k = ks*32 + q*8 + u
  short8 afrag[8];
  #pragma unroll
  for (int mt = 0; mt < 2; ++mt) {
    const int wcol = mt * 16 + nL;
    #pragma unroll
    for (int ks = 0; ks < 4; ++ks) {
      float v[8];
      #pragma unroll
      for (int u = 0; u < 8; ++u)
        v[u] = zin[zbase + (ks * 32 + q * 8 + u) * 4096 + wcol];
      U16x8 pk;
      pk.u.x = f2bf2(-2.f * v[0], -2.f * v[1]);
      pk.u.y = f2bf2(-2.f * v[2], -2.f * v[3]);
      pk.u.z = f2bf2(-2.f * v[4], -2.f * v[5]);
      pk.u.w = f2bf2(-2.f * v[6], -2.f * v[7]);
      afrag[mt * 4 + ks] = pk.s;
    }
  }

  unsigned int kmin[8];
  #pragma unroll
  for (int i = 0; i < 8; ++i) kmin[i] = 0xFFFFFFFFu;

  // ---- K loop: 16 code tiles, double-buffered register prefetch, no barriers
  const short8* __restrict__ ebs = (const short8*)ebf;   // 16B granules
  short8 bbuf[2][4];
  float  nvb[2];
  {
    const long g0 = (long)(wv * 256 + nL) * 16;
    bbuf[0][0] = ebs[g0 + 0 + q];
    bbuf[0][1] = ebs[g0 + 4 + q];
    bbuf[0][2] = ebs[g0 + 8 + q];
    bbuf[0][3] = ebs[g0 + 12 + q];
    nvb[0] = nsq1[wv * 256 + nL];
  }
  #pragma unroll 4
  for (int j = 0; j < 16; ++j) {
    const int cur = j & 1, nxt = cur ^ 1;
    if (j < 15) {
      const long g = (long)(wv * 256 + (j + 1) * 16 + nL) * 16;
      bbuf[nxt][0] = ebs[g + 0 + q];
      bbuf[nxt][1] = ebs[g + 4 + q];
      bbuf[nxt][2] = ebs[g + 8 + q];
      bbuf[nxt][3] = ebs[g + 12 + q];
      nvb[nxt] = nsq1[wv * 256 + (j + 1) * 16 + nL];
    }
    const float nv = nvb[cur];
    f32x4 a0 = {nv, nv, nv, nv};
    f32x4 a1 = {nv, nv, nv, nv};
    #pragma unroll
    for (int ks = 0; ks < 4; ++ks) {
      a0 = __builtin_amdgcn_mfma_f32_16x16x32_bf16(afrag[ks],     bbuf[cur][ks], a0, 0, 0, 0);
      a1 = __builtin_amdgcn_mfma_f32_16x16x32_bf16(afrag[4 + ks], bbuf[cur][ks], a1, 0, 0, 0);
    }
    const unsigned int rowc = (unsigned int)(wv * 256 + j * 16 + nL);
    #pragma unroll
    for (int r = 0; r < 4; ++r) {
      unsigned int k0 = (__float_as_uint(a0[r]) & 0xFFFFFC00u) | rowc;
      if (k0 < kmin[r]) kmin[r] = k0;
      unsigned int k1 = (__float_as_uint(a1[r]) & 0xFFFFFC00u) | rowc;
      if (k1 < kmin[4 + r]) kmin[4 + r] = k1;
    }
  }

  // ---- in-wave butterfly u32-min over the 16 code-lanes of each quad
  #pragma unroll
  for (int m = 1; m <= 8; m <<= 1) {
    #pragma unroll
    for (int i = 0; i < 8; ++i) {
      unsigned int o = (unsigned int)__shfl_xor((int)kmin[i], m, 64);
      if (o < kmin[i]) kmin[i] = o;
    }
  }
  if (nL == 0) {
    #pragma unroll
    for (int mt = 0; mt < 2; ++mt)
      #pragma unroll
      for (int r = 0; r < 4; ++r)
        mergeK[mt * 16 + q * 4 + r][wv] = kmin[mt * 4 + r];
  }
  __syncthreads();

  // ---- cross-wave final u32-min
  if (t < 32) {
    unsigned int b0 = mergeK[t][0], b1 = mergeK[t][1];
    unsigned int b2 = mergeK[t][2], b3 = mergeK[t][3];
    unsigned int b = min(min(b0, b1), min(b2, b3));
    int bi = (int)(b & 1023u);
    widx[t] = bi;
    used[bi] = 1;   // benign same-value race; kernel boundary = coherence point
  }
  __syncthreads();

  // ---- fp32 gather z_q + coalesced write + loss partial
  float lsum = 0.f;
  {
    const int p = t & 31, c0 = t >> 5;     // 8 channel groups x 16 ch
    const int idx = widx[p];
    const float4* erow4 = (const float4*)(cb + idx * C_DIM);
    const int obase = zbase + p;
    #pragma unroll
    for (int i4 = 0; i4 < 4; ++i4) {
      float4 ev = erow4[c0 * 4 + i4];
      int c = c0 * 16 + i4 * 4;
      #pragma unroll
      for (int u = 0; u < 4; ++u) {
        float e = (&ev.x)[u];
        int off = obase + (c + u) * 4096;
        float d = zin[off] - e;
        out[off] = e;                      // lanes over p -> coalesced
        lsum += d * d;
      }
    }
  }
  #pragma unroll
  for (int o = 32; o > 0; o >>= 1) lsum += __shfl_down(lsum, o, 64);
  if (L == 0) wsum[wv] = lsum;
  __syncthreads();
  if (t == 0) lossp[blockIdx.x] = wsum[0] + wsum[1] + wsum[2] + wsum[3];
}

// ---- F: usage count + loss finalize ----
__global__ void finalize_kernel(const int* __restrict__ used,
                                const float* __restrict__ lossp,
                                float* __restrict__ out2) {
  __shared__ int   redi[256];
  __shared__ float redf[256];
  int t = threadIdx.x;
  int s = 0;
  for (int i = t; i < K_CODES; i += 256) s += (used[i] != 0) ? 1 : 0;
  float ls = 0.f;
  for (int i = t; i < NBLK; i += 256) ls += lossp[i];
  redi[t] = s; redf[t] = ls;
  __syncthreads();
  for (int o = 128; o > 0; o >>= 1) {
    if (t < o) { redi[t] += redi[t + o]; redf[t] += redf[t + o]; }
    __syncthreads();
  }
  if (t == 0) {
    out2[0] = 1.25f * redf[0] / (float)TOT;  // (1+0.25)*MSE
    out2[1] = (float)redi[0] / 1024.0f;
  }
}

extern "C" void kernel_launch(void* const* d_in, const int* in_sizes, int n_in,
                              void* d_out, int out_size, void* d_ws, size_t ws_size,
                              hipStream_t stream) {
  const float* z  = (const float*)d_in[0];
  const float* cb = (const float*)d_in[1];
  float* out = (float*)d_out;
  char* ws = (char*)d_ws;
  unsigned short* ebf = (unsigned short*)ws;          // 262144 B
  float* nsq1  = (float*)(ws + 262144);               // 4096 B
  int*   used  = (int*)(ws + 266240);                 // 4096 B
  float* lossp = (float*)(ws + 270336);               // 8192 B (per-block partials)

  hipLaunchKernelGGL(prep_kernel, dim3(512), dim3(256), 0, stream,
                     cb, ebf, nsq1, used);
  hipLaunchKernelGGL(vq_main, dim3(NBLK), dim3(256), 0, stream,
                     z, cb, ebf, nsq1, used, lossp, out);
  hipLaunchKernelGGL(finalize_kernel, dim3(1), dim3(256), 0, stream,
                     used, lossp, out + TOT);
}

// Round 5
// 157.118 us; speedup vs baseline: 1.0022x; 1.0022x over previous
//
#include <hip/hip_runtime.h>

typedef __attribute__((ext_vector_type(8))) short short8;
typedef __attribute__((ext_vector_type(4))) float f32x4;

#define C_DIM 128
#define K_CODES 1024
#define TOT 8388608   // 16*128*64*64
#define NBLK 512      // 128 pixels (2 h-rows) per block

__device__ __forceinline__ unsigned int f2bf1(float f) {
  unsigned int u = __float_as_uint(f);
  return (u + 0x7FFFu + ((u >> 16) & 1u)) >> 16;   // RNE fp32->bf16
}
__device__ __forceinline__ unsigned int f2bf2(float lo, float hi) {
  return f2bf1(lo) | (f2bf1(hi) << 16);
}

union U16x8 { uint4 u; short8 s; };

// ---- P: bf16 codebook + (1 + ||e||^2) + zero used ----
__global__ void prep_kernel(const float* __restrict__ cb,
                            unsigned short* __restrict__ ebf,
                            float* __restrict__ nsq1,
                            int* __restrict__ used) {
  int gid = blockIdx.x * 256 + threadIdx.x;     // 512*256 == K*C exactly
  ebf[gid] = (unsigned short)f2bf1(cb[gid]);
  if (gid < K_CODES) {
    float s = 0.f;
    #pragma unroll 8
    for (int c = 0; c < C_DIM; ++c) { float v = cb[gid * C_DIM + c]; s += v * v; }
    nsq1[gid] = 1.0f + s;      // +1 keeps d positive -> u32-monotone float bits
    used[gid] = 0;
  }
}

// ---- M: block = 128 contiguous pixels (2 h-rows); wave = 32 px x ALL 1024 codes.
// DRAM-page locality is the whole point (round-4 post-mortem): every prior
// decomposition read/wrote 128B per channel at 16KB stride -> ~750 GB/s HBM
// (~10% page efficiency) and dur == hbm_bytes/750GB/s in ALL rounds. This
// block shape touches 512B contiguous per channel, with adjacent co-resident
// blocks tiling adjacent slices.
// Math (verified R4): A = bf16(-2z), MFMA C init = 1+||e||^2 -> d directly;
// key = (bits(d) & ~1023) | code; argmin via u32 min. launch_bounds(256,4):
// live set ~100 regs, MUST stay under 128 (R2 spill cost 1.5GB HBM).
__global__ __launch_bounds__(256, 4)
void vq_main(const float* __restrict__ zin, const float* __restrict__ cb,
             const unsigned short* __restrict__ ebf,
             const float* __restrict__ nsq1,
             int* __restrict__ used, float* __restrict__ lossp,
             float* __restrict__ out) {
  __shared__ int   widx[128];
  __shared__ float wsum[4];

  const int t  = threadIdx.x;
  const int L  = t & 63;
  const int wv = t >> 6;        // wave 0..3: pixels [wv*32, wv*32+32)
  const int q  = L >> 4;        // lane quad
  const int nL = L & 15;

  const int bb = blockIdx.x >> 5;          // batch 0..15
  const int hg = blockIdx.x & 31;          // 2-row group 0..31
  const int zoff = bb * (C_DIM * 4096) + hg * 128;   // + c*4096 + p, p in [0,128)

  // ---- A fragments straight from global, packed bf16(-2z) in-register
  // lane L, m-tile mt: pixel = wv*32 + mt*16 + nL, k = ks*32 + q*8 + u
  short8 afrag[8];
  #pragma unroll
  for (int mt = 0; mt < 2; ++mt) {
    const int wcol = wv * 32 + mt * 16 + nL;
    #pragma unroll
    for (int ks = 0; ks < 4; ++ks) {
      float v[8];
      #pragma unroll
      for (int u = 0; u < 8; ++u)
        v[u] = zin[zoff + (ks * 32 + q * 8 + u) * 4096 + wcol];
      U16x8 pk;
      pk.u.x = f2bf2(-2.f * v[0], -2.f * v[1]);
      pk.u.y = f2bf2(-2.f * v[2], -2.f * v[3]);
      pk.u.z = f2bf2(-2.f * v[4], -2.f * v[5]);
      pk.u.w = f2bf2(-2.f * v[6], -2.f * v[7]);
      afrag[mt * 4 + ks] = pk.s;
    }
  }

  unsigned int kmin[8];
  #pragma unroll
  for (int i = 0; i < 8; ++i) kmin[i] = 0xFFFFFFFFu;

  // ---- K loop: 64 code tiles (all 1024 codes), double-buffered register
  // prefetch from the L2-hot 256KB bf16 codebook; no barriers.
  const short8* __restrict__ ebs = (const short8*)ebf;   // 16B granules
  short8 bbuf[2][4];
  float  nvb[2];
  {
    const long g0 = (long)nL * 16;
    bbuf[0][0] = ebs[g0 + 0 + q];
    bbuf[0][1] = ebs[g0 + 4 + q];
    bbuf[0][2] = ebs[g0 + 8 + q];
    bbuf[0][3] = ebs[g0 + 12 + q];
    nvb[0] = nsq1[nL];
  }
  #pragma unroll 4
  for (int j = 0; j < 64; ++j) {
    const int cur = j & 1, nxt = cur ^ 1;
    if (j < 63) {
      const int rn = (j + 1) * 16 + nL;
      const long g = (long)rn * 16;
      bbuf[nxt][0] = ebs[g + 0 + q];
      bbuf[nxt][1] = ebs[g + 4 + q];
      bbuf[nxt][2] = ebs[g + 8 + q];
      bbuf[nxt][3] = ebs[g + 12 + q];
      nvb[nxt] = nsq1[rn];
    }
    const float nv = nvb[cur];
    f32x4 a0 = {nv, nv, nv, nv};
    f32x4 a1 = {nv, nv, nv, nv};
    #pragma unroll
    for (int ks = 0; ks < 4; ++ks) {
      a0 = __builtin_amdgcn_mfma_f32_16x16x32_bf16(afrag[ks],     bbuf[cur][ks], a0, 0, 0, 0);
      a1 = __builtin_amdgcn_mfma_f32_16x16x32_bf16(afrag[4 + ks], bbuf[cur][ks], a1, 0, 0, 0);
    }
    const unsigned int rowc = (unsigned int)(j * 16 + nL);
    #pragma unroll
    for (int r = 0; r < 4; ++r) {
      unsigned int k0 = (__float_as_uint(a0[r]) & 0xFFFFFC00u) | rowc;
      if (k0 < kmin[r]) kmin[r] = k0;
      unsigned int k1 = (__float_as_uint(a1[r]) & 0xFFFFFC00u) | rowc;
      if (k1 < kmin[4 + r]) kmin[4 + r] = k1;
    }
  }

  // ---- in-wave butterfly u32-min over the 16 code-lanes of each quad
  #pragma unroll
  for (int m = 1; m <= 8; m <<= 1) {
    #pragma unroll
    for (int i = 0; i < 8; ++i) {
      unsigned int o = (unsigned int)__shfl_xor((int)kmin[i], m, 64);
      if (o < kmin[i]) kmin[i] = o;
    }
  }
  if (nL == 0) {
    #pragma unroll
    for (int mt = 0; mt < 2; ++mt)
      #pragma unroll
      for (int r = 0; r < 4; ++r) {
        int bi = (int)(kmin[mt * 4 + r] & 1023u);
        widx[wv * 32 + mt * 16 + q * 4 + r] = bi;
        used[bi] = 1;   // benign same-value race; kernel boundary = coherence
      }
  }
  __syncthreads();

  // ---- fp32 gather z_q + contiguous 256B-coalesced write + loss partial
  float lsum = 0.f;
  {
    const int p = t & 127, cg = t >> 7;    // 2 channel groups x 64 ch
    const int idx = widx[p];
    const float4* erow4 = (const float4*)(cb + idx * C_DIM + cg * 64);
    const int obase = zoff + cg * 64 * 4096 + p;
    #pragma unroll 4
    for (int i4 = 0; i4 < 16; ++i4) {
      float4 ev = erow4[i4];
      #pragma unroll
      for (int u = 0; u < 4; ++u) {
        float e = (&ev.x)[u];
        int off = obase + (i4 * 4 + u) * 4096;
        float d = zin[off] - e;
        out[off] = e;                      // 64 lanes over p -> 256B contiguous
        lsum += d * d;
      }
    }
  }
  #pragma unroll
  for (int o = 32; o > 0; o >>= 1) lsum += __shfl_down(lsum, o, 64);
  if (L == 0) wsum[wv] = lsum;
  __syncthreads();
  if (t == 0) lossp[blockIdx.x] = wsum[0] + wsum[1] + wsum[2] + wsum[3];
}

// ---- F: usage count + loss finalize ----
__global__ void finalize_kernel(const int* __restrict__ used,
                                const float* __restrict__ lossp,
                                float* __restrict__ out2) {
  __shared__ int   redi[256];
  __shared__ float redf[256];
  int t = threadIdx.x;
  int s = 0;
  for (int i = t; i < K_CODES; i += 256) s += (used[i] != 0) ? 1 : 0;
  float ls = 0.f;
  for (int i = t; i < NBLK; i += 256) ls += lossp[i];
  redi[t] = s; redf[t] = ls;
  __syncthreads();
  for (int o = 128; o > 0; o >>= 1) {
    if (t < o) { redi[t] += redi[t + o]; redf[t] += redf[t + o]; }
    __syncthreads();
  }
  if (t == 0) {
    out2[0] = 1.25f * redf[0] / (float)TOT;  // (1+0.25)*MSE
    out2[1] = (float)redi[0] / 1024.0f;
  }
}

extern "C" void kernel_launch(void* const* d_in, const int* in_sizes, int n_in,
                              void* d_out, int out_size, void* d_ws, size_t ws_size,
                              hipStream_t stream) {
  const float* z  = (const float*)d_in[0];
  const float* cb = (const float*)d_in[1];
  float* out = (float*)d_out;
  char* ws = (char*)d_ws;
  unsigned short* ebf = (unsigned short*)ws;          // 262144 B
  float* nsq1  = (float*)(ws + 262144);               // 4096 B
  int*   used  = (int*)(ws + 266240);                 // 4096 B
  float* lossp = (float*)(ws + 270336);               // 2048 B (per-block partials)

  hipLaunchKernelGGL(prep_kernel, dim3(512), dim3(256), 0, stream,
                     cb, ebf, nsq1, used);
  hipLaunchKernelGGL(vq_main, dim3(NBLK), dim3(256), 0, stream,
                     z, cb, ebf, nsq1, used, lossp, out);
  hipLaunchKernelGGL(finalize_kernel, dim3(1), dim3(256), 0, stream,
                     used, lossp, out + TOT);
}

// Round 6
// 119.468 us; speedup vs baseline: 1.3181x; 1.3151x over previous
//
#include <hip/hip_runtime.h>

typedef __attribute__((ext_vector_type(8))) short short8;
typedef __attribute__((ext_vector_type(4))) float f32x4;

#define C_DIM 128
#define K_CODES 1024
#define TOT 8388608   // 16*128*64*64
#define NBLK 512      // 128 contiguous pixels per block

__device__ __forceinline__ unsigned int f2bf1(float f) {
  unsigned int u = __float_as_uint(f);
  return (u + 0x7FFFu + ((u >> 16) & 1u)) >> 16;   // RNE fp32->bf16
}
__device__ __forceinline__ unsigned int f2bf2(float lo, float hi) {
  return f2bf1(lo) | (f2bf1(hi) << 16);
}

union U16x8 { uint4 u; short8 s; };

// ---- P: bf16 codebook + (1 + ||e||^2) + zero used ----
__global__ void prep_kernel(const float* __restrict__ cb,
                            unsigned short* __restrict__ ebf,
                            float* __restrict__ nsq1,
                            int* __restrict__ used) {
  int gid = blockIdx.x * 256 + threadIdx.x;     // 512*256 == K*C exactly
  ebf[gid] = (unsigned short)f2bf1(cb[gid]);
  if (gid < K_CODES) {
    float s = 0.f;
    #pragma unroll 8
    for (int c = 0; c < C_DIM; ++c) { float v = cb[gid * C_DIM + c]; s += v * v; }
    nsq1[gid] = 1.0f + s;      // +1 keeps d positive -> u32-monotone float bits
    used[gid] = 0;
  }
}

// ---- M: block = 128 px; wave = 32 px x ALL 1024 codes; B shared via LDS ----
// Round-5 post-mortem: the invariant wall (~80us in R1/R3/R4/R5) tracks per-CU
// VMEM line transactions (~45K/CU), not HBM BW / occupancy / VALU. This version
// stages each codebook line into the CU ONCE PER BLOCK (contiguous 1KB/instr),
// double-buffered 64-code chunks, one barrier per chunk: B-path 32K -> 8K
// lines/CU. Epilogue gathers bf16 rows (half lines; +<=2e-6 error).
// Math (verified R4/R5): A=bf16(-2z), MFMA C-init = 1+||e||^2 -> d directly;
// key=(bits(d)&~1023)|code, argmin via u32 min. Regs ~95: (256,4), NO spills
// (R2: spill cost 1.5GB HBM traffic).
__global__ __launch_bounds__(256, 4)
void vq_main(const float* __restrict__ zin, const float* __restrict__ cb,
             const unsigned short* __restrict__ ebf,
             const float* __restrict__ nsq1,
             int* __restrict__ used, float* __restrict__ lossp,
             float* __restrict__ out) {
  __shared__ __align__(16) uint4 bG[2][1024];   // 2 x 16KB: 64-code chunks
  __shared__ float nsq_s[K_CODES];
  __shared__ int   widx[128];
  __shared__ float wsum[4];

  const int t  = threadIdx.x;
  const int L  = t & 63;
  const int wv = t >> 6;        // wave 0..3: pixels [wv*32, wv*32+32)
  const int q  = L >> 4;        // lane quad
  const int nL = L & 15;

  const int bb = blockIdx.x >> 5;          // batch 0..15
  const int hg = blockIdx.x & 31;          // 128-px group
  const int zoff = bb * (C_DIM * 4096) + hg * 128;   // + c*4096 + p

  for (int i = t; i < K_CODES; i += 256) nsq_s[i] = nsq1[i];

  // ---- A fragments straight from global, packed bf16(-2z) in-register
  // lane L, m-tile mt: pixel = wv*32 + mt*16 + nL, k = ks*32 + q*8 + u
  short8 afrag[8];
  #pragma unroll
  for (int mt = 0; mt < 2; ++mt) {
    const int wcol = wv * 32 + mt * 16 + nL;
    #pragma unroll
    for (int ks = 0; ks < 4; ++ks) {
      float v[8];
      #pragma unroll
      for (int u = 0; u < 8; ++u)
        v[u] = zin[zoff + (ks * 32 + q * 8 + u) * 4096 + wcol];
      U16x8 pk;
      pk.u.x = f2bf2(-2.f * v[0], -2.f * v[1]);
      pk.u.y = f2bf2(-2.f * v[2], -2.f * v[3]);
      pk.u.z = f2bf2(-2.f * v[4], -2.f * v[5]);
      pk.u.w = f2bf2(-2.f * v[6], -2.f * v[7]);
      afrag[mt * 4 + ks] = pk.s;
    }
  }

  // ---- staging thread roles (contiguous 1KB per wave-instruction)
  const uint4* __restrict__ ebv = (const uint4*)ebf;   // granule view, row=16
  const int nLw = t >> 4;        // row-within-group 0..15
  const int oct = t & 15;        // granule-within-row
  const int sks = oct >> 2, sq = oct & 3;

  // stage chunk 0
  #pragma unroll
  for (int p = 0; p < 4; ++p) {
    int r = p * 16 + nLw;                        // row within chunk
    bG[0][p * 256 + sks * 64 + nLw * 4 + sq] = ebv[r * 16 + oct];
  }
  __syncthreads();

  unsigned int kmin[8];
  #pragma unroll
  for (int i = 0; i < 8; ++i) kmin[i] = 0xFFFFFFFFu;

  // ---- K loop: 16 chunks x 4 j-tiles; double-buffered, 1 barrier/chunk
  #pragma unroll 1
  for (int ch = 0; ch < 16; ++ch) {
    const int cur = ch & 1;
    if (ch < 15) {                               // stage next chunk into !cur
      #pragma unroll
      for (int p = 0; p < 4; ++p) {
        int r = p * 16 + nLw;
        bG[cur ^ 1][p * 256 + sks * 64 + nLw * 4 + sq] =
            ebv[((ch + 1) * 64 + r) * 16 + oct];
      }
    }
    const short8* bp = (const short8*)bG[cur];
    #pragma unroll
    for (int jj = 0; jj < 4; ++jj) {
      const int row = ch * 64 + jj * 16 + nL;    // this lane's code
      short8 b0 = bp[jj * 256 + 0 * 64 + nL * 4 + q];
      short8 b1 = bp[jj * 256 + 1 * 64 + nL * 4 + q];
      short8 b2 = bp[jj * 256 + 2 * 64 + nL * 4 + q];
      short8 b3 = bp[jj * 256 + 3 * 64 + nL * 4 + q];
      const float nv = nsq_s[row];
      f32x4 a0 = {nv, nv, nv, nv};
      f32x4 a1 = {nv, nv, nv, nv};
      a0 = __builtin_amdgcn_mfma_f32_16x16x32_bf16(afrag[0], b0, a0, 0, 0, 0);
      a1 = __builtin_amdgcn_mfma_f32_16x16x32_bf16(afrag[4], b0, a1, 0, 0, 0);
      a0 = __builtin_amdgcn_mfma_f32_16x16x32_bf16(afrag[1], b1, a0, 0, 0, 0);
      a1 = __builtin_amdgcn_mfma_f32_16x16x32_bf16(afrag[5], b1, a1, 0, 0, 0);
      a0 = __builtin_amdgcn_mfma_f32_16x16x32_bf16(afrag[2], b2, a0, 0, 0, 0);
      a1 = __builtin_amdgcn_mfma_f32_16x16x32_bf16(afrag[6], b2, a1, 0, 0, 0);
      a0 = __builtin_amdgcn_mfma_f32_16x16x32_bf16(afrag[3], b3, a0, 0, 0, 0);
      a1 = __builtin_amdgcn_mfma_f32_16x16x32_bf16(afrag[7], b3, a1, 0, 0, 0);
      const unsigned int rowc = (unsigned int)row;
      #pragma unroll
      for (int r = 0; r < 4; ++r) {
        unsigned int k0 = (__float_as_uint(a0[r]) & 0xFFFFFC00u) | rowc;
        if (k0 < kmin[r]) kmin[r] = k0;
        unsigned int k1 = (__float_as_uint(a1[r]) & 0xFFFFFC00u) | rowc;
        if (k1 < kmin[4 + r]) kmin[4 + r] = k1;
      }
    }
    __syncthreads();   // next-chunk writes visible; cur free for re-stage
  }

  // ---- in-wave butterfly u32-min over the 16 code-lanes of each quad
  #pragma unroll
  for (int m = 1; m <= 8; m <<= 1) {
    #pragma unroll
    for (int i = 0; i < 8; ++i) {
      unsigned int o = (unsigned int)__shfl_xor((int)kmin[i], m, 64);
      if (o < kmin[i]) kmin[i] = o;
    }
  }
  if (nL == 0) {
    #pragma unroll
    for (int mt = 0; mt < 2; ++mt)
      #pragma unroll
      for (int r = 0; r < 4; ++r) {
        int bi = (int)(kmin[mt * 4 + r] & 1023u);
        widx[wv * 32 + mt * 16 + q * 4 + r] = bi;
        used[bi] = 1;   // benign same-value race; kernel boundary = coherence
      }
  }
  __syncthreads();

  // ---- gather bf16 e-row + coalesced z/out + loss partial
  float lsum = 0.f;
  {
    const int p = t & 127, cg = t >> 7;    // 2 channel halves x 64 ch
    const int idx = widx[p];
    const uint4* erow = ebv + idx * 16 + cg * 8;
    const int obase = zoff + cg * 64 * 4096 + p;
    #pragma unroll 2
    for (int i = 0; i < 8; ++i) {
      uint4 g = erow[i];
      const unsigned int wrd[4] = {g.x, g.y, g.z, g.w};
      #pragma unroll
      for (int half = 0; half < 4; ++half) {
        float e0 = __uint_as_float(wrd[half] << 16);
        float e1 = __uint_as_float(wrd[half] & 0xFFFF0000u);
        int off = obase + (i * 8 + half * 2) * 4096;
        float d0 = zin[off] - e0;
        out[off] = e0;                     // lanes over p -> 256B contiguous
        lsum += d0 * d0;
        off += 4096;
        float d1 = zin[off] - e1;
        out[off] = e1;
        lsum += d1 * d1;
      }
    }
  }
  #pragma unroll
  for (int o = 32; o > 0; o >>= 1) lsum += __shfl_down(lsum, o, 64);
  if (L == 0) wsum[wv] = lsum;
  __syncthreads();
  if (t == 0) lossp[blockIdx.x] = wsum[0] + wsum[1] + wsum[2] + wsum[3];
}

// ---- F: usage count + loss finalize ----
__global__ void finalize_kernel(const int* __restrict__ used,
                                const float* __restrict__ lossp,
                                float* __restrict__ out2) {
  __shared__ int   redi[256];
  __shared__ float redf[256];
  int t = threadIdx.x;
  int s = 0;
  for (int i = t; i < K_CODES; i += 256) s += (used[i] != 0) ? 1 : 0;
  float ls = 0.f;
  for (int i = t; i < NBLK; i += 256) ls += lossp[i];
  redi[t] = s; redf[t] = ls;
  __syncthreads();
  for (int o = 128; o > 0; o >>= 1) {
    if (t < o) { redi[t] += redi[t + o]; redf[t] += redf[t + o]; }
    __syncthreads();
  }
  if (t == 0) {
    out2[0] = 1.25f * redf[0] / (float)TOT;  // (1+0.25)*MSE
    out2[1] = (float)redi[0] / 1024.0f;
  }
}

extern "C" void kernel_launch(void* const* d_in, const int* in_sizes, int n_in,
                              void* d_out, int out_size, void* d_ws, size_t ws_size,
                              hipStream_t stream) {
  const float* z  = (const float*)d_in[0];
  const float* cb = (const float*)d_in[1];
  float* out = (float*)d_out;
  char* ws = (char*)d_ws;
  unsigned short* ebf = (unsigned short*)ws;          // 262144 B
  float* nsq1  = (float*)(ws + 262144);               // 4096 B
  int*   used  = (int*)(ws + 266240);                 // 4096 B
  float* lossp = (float*)(ws + 270336);               // 2048 B (per-block partials)

  hipLaunchKernelGGL(prep_kernel, dim3(512), dim3(256), 0, stream,
                     cb, ebf, nsq1, used);
  hipLaunchKernelGGL(vq_main, dim3(NBLK), dim3(256), 0, stream,
                     z, cb, ebf, nsq1, used, lossp, out);
  hipLaunchKernelGGL(finalize_kernel, dim3(1), dim3(256), 0, stream,
                     used, lossp, out + TOT);
}

// Round 7
// 117.457 us; speedup vs baseline: 1.3406x; 1.0171x over previous
//
#include <hip/hip_runtime.h>

typedef __attribute__((ext_vector_type(8))) short short8;
typedef __attribute__((ext_vector_type(4))) float f32x4;

#define C_DIM 128
#define K_CODES 1024
#define TOT 8388608   // 16*128*64*64
#define NBLK 512      // 128 contiguous pixels per block

__device__ __forceinline__ unsigned int f2bf1(float f) {
  unsigned int u = __float_as_uint(f);
  return (u + 0x7FFFu + ((u >> 16) & 1u)) >> 16;   // RNE fp32->bf16
}
__device__ __forceinline__ unsigned int f2bf2(float lo, float hi) {
  return f2bf1(lo) | (f2bf1(hi) << 16);
}

union U16x8 { uint4 u; short8 s; };

// ---- P: bf16 codebook + (1 + ||e||^2) + zero used ----
__global__ void prep_kernel(const float* __restrict__ cb,
                            unsigned short* __restrict__ ebf,
                            float* __restrict__ nsq1,
                            int* __restrict__ used) {
  int gid = blockIdx.x * 256 + threadIdx.x;     // 512*256 == K*C exactly
  ebf[gid] = (unsigned short)f2bf1(cb[gid]);
  if (gid < K_CODES) {
    float s = 0.f;
    #pragma unroll 8
    for (int c = 0; c < C_DIM; ++c) { float v = cb[gid * C_DIM + c]; s += v * v; }
    nsq1[gid] = 1.0f + s;      // +1 keeps d positive -> u32-monotone float bits
    used[gid] = 0;
  }
}

// ---- M: block = 128 px; wave = 64 px x 512 codes (half-split); B via LDS ----
// R6 post-mortem: LDS-shared B staging cut vq_main 79 -> ~38us (VMEM-line
// theory confirmed). New wall: ds_read_b128 throughput (2048 instr/CU ~10us).
// This round: each wave owns 64 px x half the codes -> per-wave B ds_reads
// 256 -> 128 (same MFMA count), total ds_reads/CU halves. Wave pair merges
// per-pixel argmin keys via LDS (2-way u32 min).
// Math (verified R4-R6): A=bf16(-2z), MFMA C-init = 1+||e||^2 -> d directly;
// key=(bits(d)&~1023)|code, argmin via u32 min.
// launch_bounds(256,3): ~170 reg cap, live set ~140 (NO spill — R2 lesson);
// grid 512 = exactly 2 blocks/CU either way, so (,3) costs nothing vs (,4).
__global__ __launch_bounds__(256, 3)
void vq_main(const float* __restrict__ zin, const float* __restrict__ cb,
             const unsigned short* __restrict__ ebf,
             const float* __restrict__ nsq1,
             int* __restrict__ used, float* __restrict__ lossp,
             float* __restrict__ out) {
  __shared__ __align__(16) uint4 bG[2][1024];   // 2 x 16KB: 64-code chunks
  __shared__ float nsq_s[K_CODES];
  __shared__ unsigned int mergeK[128][2];
  __shared__ int   widx[128];
  __shared__ float wsum[4];

  const int t  = threadIdx.x;
  const int L  = t & 63;
  const int wv = t >> 6;        // wave 0..3
  const int ph = wv >> 1;       // pixel half: px [ph*64, ph*64+64)
  const int kh = wv & 1;        // code half: jj tiles {kh*2, kh*2+1}
  const int q  = L >> 4;        // lane quad
  const int nL = L & 15;

  const int bb = blockIdx.x >> 5;          // batch 0..15
  const int hg = blockIdx.x & 31;          // 128-px group
  const int zoff = bb * (C_DIM * 4096) + hg * 128;   // + c*4096 + p

  for (int i = t; i < K_CODES; i += 256) nsq_s[i] = nsq1[i];

  // ---- A fragments straight from global, packed bf16(-2z) in-register
  // lane L, m-tile mt (0..3): pixel = ph*64 + mt*16 + nL, k = ks*32 + q*8 + u
  short8 afrag[16];
  #pragma unroll
  for (int mt = 0; mt < 4; ++mt) {
    const int wcol = ph * 64 + mt * 16 + nL;
    #pragma unroll
    for (int ks = 0; ks < 4; ++ks) {
      float v[8];
      #pragma unroll
      for (int u = 0; u < 8; ++u)
        v[u] = zin[zoff + (ks * 32 + q * 8 + u) * 4096 + wcol];
      U16x8 pk;
      pk.u.x = f2bf2(-2.f * v[0], -2.f * v[1]);
      pk.u.y = f2bf2(-2.f * v[2], -2.f * v[3]);
      pk.u.z = f2bf2(-2.f * v[4], -2.f * v[5]);
      pk.u.w = f2bf2(-2.f * v[6], -2.f * v[7]);
      afrag[mt * 4 + ks] = pk.s;
    }
  }

  // ---- staging thread roles (contiguous 1KB per wave-instruction)
  const uint4* __restrict__ ebv = (const uint4*)ebf;   // granule view, row=16
  const int nLw = t >> 4;        // row-within-group 0..15
  const int oct = t & 15;        // granule-within-row
  const int sks = oct >> 2, sq = oct & 3;

  // stage chunk 0
  #pragma unroll
  for (int p = 0; p < 4; ++p) {
    int r = p * 16 + nLw;                        // row within chunk
    bG[0][p * 256 + sks * 64 + nLw * 4 + sq] = ebv[r * 16 + oct];
  }
  __syncthreads();

  unsigned int kmin[16];
  #pragma unroll
  for (int i = 0; i < 16; ++i) kmin[i] = 0xFFFFFFFFu;

  // ---- K loop: 16 chunks; this wave consumes its 2 jj-tiles (32 codes)
  #pragma unroll 1
  for (int ch = 0; ch < 16; ++ch) {
    const int cur = ch & 1;
    if (ch < 15) {                               // stage next chunk into !cur
      #pragma unroll
      for (int p = 0; p < 4; ++p) {
        int r = p * 16 + nLw;
        bG[cur ^ 1][p * 256 + sks * 64 + nLw * 4 + sq] =
            ebv[((ch + 1) * 64 + r) * 16 + oct];
      }
    }
    const short8* bp = (const short8*)bG[cur];
    #pragma unroll
    for (int j2 = 0; j2 < 2; ++j2) {
      const int jj = kh * 2 + j2;
      const int row = ch * 64 + jj * 16 + nL;    // this lane's code
      short8 b0 = bp[jj * 256 + 0 * 64 + nL * 4 + q];
      short8 b1 = bp[jj * 256 + 1 * 64 + nL * 4 + q];
      short8 b2 = bp[jj * 256 + 2 * 64 + nL * 4 + q];
      short8 b3 = bp[jj * 256 + 3 * 64 + nL * 4 + q];
      const float nv = nsq_s[row];
      f32x4 a0 = {nv, nv, nv, nv};
      f32x4 a1 = {nv, nv, nv, nv};
      f32x4 a2 = {nv, nv, nv, nv};
      f32x4 a3 = {nv, nv, nv, nv};
      a0 = __builtin_amdgcn_mfma_f32_16x16x32_bf16(afrag[0],  b0, a0, 0, 0, 0);
      a1 = __builtin_amdgcn_mfma_f32_16x16x32_bf16(afrag[4],  b0, a1, 0, 0, 0);
      a2 = __builtin_amdgcn_mfma_f32_16x16x32_bf16(afrag[8],  b0, a2, 0, 0, 0);
      a3 = __builtin_amdgcn_mfma_f32_16x16x32_bf16(afrag[12], b0, a3, 0, 0, 0);
      a0 = __builtin_amdgcn_mfma_f32_16x16x32_bf16(afrag[1],  b1, a0, 0, 0, 0);
      a1 = __builtin_amdgcn_mfma_f32_16x16x32_bf16(afrag[5],  b1, a1, 0, 0, 0);
      a2 = __builtin_amdgcn_mfma_f32_16x16x32_bf16(afrag[9],  b1, a2, 0, 0, 0);
      a3 = __builtin_amdgcn_mfma_f32_16x16x32_bf16(afrag[13], b1, a3, 0, 0, 0);
      a0 = __builtin_amdgcn_mfma_f32_16x16x32_bf16(afrag[2],  b2, a0, 0, 0, 0);
      a1 = __builtin_amdgcn_mfma_f32_16x16x32_bf16(afrag[6],  b2, a1, 0, 0, 0);
      a2 = __builtin_amdgcn_mfma_f32_16x16x32_bf16(afrag[10], b2, a2, 0, 0, 0);
      a3 = __builtin_amdgcn_mfma_f32_16x16x32_bf16(afrag[14], b2, a3, 0, 0, 0);
      a0 = __builtin_amdgcn_mfma_f32_16x16x32_bf16(afrag[3],  b3, a0, 0, 0, 0);
      a1 = __builtin_amdgcn_mfma_f32_16x16x32_bf16(afrag[7],  b3, a1, 0, 0, 0);
      a2 = __builtin_amdgcn_mfma_f32_16x16x32_bf16(afrag[11], b3, a2, 0, 0, 0);
      a3 = __builtin_amdgcn_mfma_f32_16x16x32_bf16(afrag[15], b3, a3, 0, 0, 0);
      const unsigned int rowc = (unsigned int)row;
      #pragma unroll
      for (int r = 0; r < 4; ++r) {
        unsigned int k0 = (__float_as_uint(a0[r]) & 0xFFFFFC00u) | rowc;
        if (k0 < kmin[r]) kmin[r] = k0;
        unsigned int k1 = (__float_as_uint(a1[r]) & 0xFFFFFC00u) | rowc;
        if (k1 < kmin[4 + r]) kmin[4 + r] = k1;
        unsigned int k2 = (__float_as_uint(a2[r]) & 0xFFFFFC00u) | rowc;
        if (k2 < kmin[8 + r]) kmin[8 + r] = k2;
        unsigned int k3 = (__float_as_uint(a3[r]) & 0xFFFFFC00u) | rowc;
        if (k3 < kmin[12 + r]) kmin[12 + r] = k3;
      }
    }
    __syncthreads();   // next-chunk writes visible; cur free for re-stage
  }

  // ---- in-wave butterfly u32-min over the 16 code-lanes of each quad
  #pragma unroll
  for (int m = 1; m <= 8; m <<= 1) {
    #pragma unroll
    for (int i = 0; i < 16; ++i) {
      unsigned int o = (unsigned int)__shfl_xor((int)kmin[i], m, 64);
      if (o < kmin[i]) kmin[i] = o;
    }
  }
  if (nL == 0) {
    #pragma unroll
    for (int mt = 0; mt < 4; ++mt)
      #pragma unroll
      for (int r = 0; r < 4; ++r)
        mergeK[ph * 64 + mt * 16 + q * 4 + r][kh] = kmin[mt * 4 + r];
  }
  __syncthreads();

  // ---- cross-half merge (2-way u32 min per pixel)
  if (t < 128) {
    unsigned int b = min(mergeK[t][0], mergeK[t][1]);
    int bi = (int)(b & 1023u);
    widx[t] = bi;
    used[bi] = 1;   // benign same-value race; kernel boundary = coherence
  }
  __syncthreads();

  // ---- gather bf16 e-row + coalesced z/out + loss partial
  float lsum = 0.f;
  {
    const int p = t & 127, cg = t >> 7;    // 2 channel halves x 64 ch
    const int idx = widx[p];
    const uint4* erow = ebv + idx * 16 + cg * 8;
    const int obase = zoff + cg * 64 * 4096 + p;
    #pragma unroll 2
    for (int i = 0; i < 8; ++i) {
      uint4 g = erow[i];
      const unsigned int wrd[4] = {g.x, g.y, g.z, g.w};
      #pragma unroll
      for (int half = 0; half < 4; ++half) {
        float e0 = __uint_as_float(wrd[half] << 16);
        float e1 = __uint_as_float(wrd[half] & 0xFFFF0000u);
        int off = obase + (i * 8 + half * 2) * 4096;
        float d0 = zin[off] - e0;
        out[off] = e0;                     // lanes over p -> 256B contiguous
        lsum += d0 * d0;
        off += 4096;
        float d1 = zin[off] - e1;
        out[off] = e1;
        lsum += d1 * d1;
      }
    }
  }
  #pragma unroll
  for (int o = 32; o > 0; o >>= 1) lsum += __shfl_down(lsum, o, 64);
  if (L == 0) wsum[wv] = lsum;
  __syncthreads();
  if (t == 0) lossp[blockIdx.x] = wsum[0] + wsum[1] + wsum[2] + wsum[3];
}

// ---- F: usage count + loss finalize ----
__global__ void finalize_kernel(const int* __restrict__ used,
                                const float* __restrict__ lossp,
                                float* __restrict__ out2) {
  __shared__ int   redi[256];
  __shared__ float redf[256];
  int t = threadIdx.x;
  int s = 0;
  for (int i = t; i < K_CODES; i += 256) s += (used[i] != 0) ? 1 : 0;
  float ls = 0.f;
  for (int i = t; i < NBLK; i += 256) ls += lossp[i];
  redi[t] = s; redf[t] = ls;
  __syncthreads();
  for (int o = 128; o > 0; o >>= 1) {
    if (t < o) { redi[t] += redi[t + o]; redf[t] += redf[t + o]; }
    __syncthreads();
  }
  if (t == 0) {
    out2[0] = 1.25f * redf[0] / (float)TOT;  // (1+0.25)*MSE
    out2[1] = (float)redi[0] / 1024.0f;
  }
}

extern "C" void kernel_launch(void* const* d_in, const int* in_sizes, int n_in,
                              void* d_out, int out_size, void* d_ws, size_t ws_size,
                              hipStream_t stream) {
  const float* z  = (const float*)d_in[0];
  const float* cb = (const float*)d_in[1];
  float* out = (float*)d_out;
  char* ws = (char*)d_ws;
  unsigned short* ebf = (unsigned short*)ws;          // 262144 B
  float* nsq1  = (float*)(ws + 262144);               // 4096 B
  int*   used  = (int*)(ws + 266240);                 // 4096 B
  float* lossp = (float*)(ws + 270336);               // 2048 B (per-block partials)

  hipLaunchKernelGGL(prep_kernel, dim3(512), dim3(256), 0, stream,
                     cb, ebf, nsq1, used);
  hipLaunchKernelGGL(vq_main, dim3(NBLK), dim3(256), 0, stream,
                     z, cb, ebf, nsq1, used, lossp, out);
  hipLaunchKernelGGL(finalize_kernel, dim3(1), dim3(256), 0, stream,
                     used, lossp, out + TOT);
}